// Round 15
// baseline (42.500 us; speedup 1.0000x reference)
//
#include <hip/hip_runtime.h>

// out[b,n] = q^T W_n p ; p=emb[b,R(n)], q=emb[b,C(n)], W_n=kern[:,n,:]
// R15: ABLATION PROBE = R7 (best, 29.17us) with the main pair loop executed
// TWICE (identical pairs, idempotent duplicate stores). dur delta vs R7
// isolates the pair-loop's true cost, which has been invisible below the
// harness's 40us poison fills. Everything else is bit-identical to R7.

#define B_TOT 2048
#define NF    32
#define EMB   64
#define NP    496
#define BT    32

typedef short bf16x8 __attribute__((ext_vector_type(8)));
typedef short bf16x4 __attribute__((ext_vector_type(4)));
typedef float f32x4  __attribute__((ext_vector_type(4)));

static __device__ inline unsigned f2bf(float f) {          // RNE f32->bf16
    unsigned u = __builtin_bit_cast(unsigned, f);
    u += 0x7fffu + ((u >> 16) & 1u);
    return u >> 16;
}
static __device__ inline unsigned pack2(float lo, float hi) {
    return f2bf(lo) | (f2bf(hi) << 16);
}
static __device__ inline float bf2f(short s) {
    return __builtin_bit_cast(float, (unsigned)((unsigned short)s) << 16);
}

#define AS1 __attribute__((address_space(1)))
#define AS3 __attribute__((address_space(3)))

// ---- fused prep: blocks [0,496) = kern cvt ; blocks [496, 496+2048) = emb cvt
__global__ __launch_bounds__(256) void prep(const float* __restrict__ kern,
                                            const float* __restrict__ emb,
                                            short* __restrict__ kb,
                                            short* __restrict__ ebf) {
    __shared__ short w[EMB * 72];
    if (blockIdx.x < NP) {
        const int n = blockIdx.x;
#pragma unroll
        for (int j = 0; j < 4; ++j) {
            const int idx = threadIdx.x + 256 * j;        // (h, e4)
            const int h = idx >> 4, e4 = idx & 15;
            const f32x4 v = *(const f32x4*)(kern + ((size_t)h * NP + n) * EMB + e4 * 4);
            uint2 u;
            u.x = pack2(v[0], v[1]);
            u.y = pack2(v[2], v[3]);
            *(uint2*)&w[h * 72 + e4 * 4] = u;
        }
        __syncthreads();
#pragma unroll
        for (int j = 0; j < 2; ++j) {
            const int u    = threadIdx.x + 256 * j;       // fragment-lane unit
            const int frag = u >> 6, l = u & 63;
            const int h  = (frag >> 1) * 16 + (l & 15);
            const int e0 = (frag & 1) * 32 + (l >> 4) * 8;
            const bf16x8 t = *(const bf16x8*)&w[h * 72 + e0];
            *(bf16x8*)(kb + (size_t)n * 4096 + u * 8) = t;
        }
    } else {
        // emb -> chunk-swizzled bf16
        const int t    = (blockIdx.x - NP) * 256 + threadIdx.x;  // 0..524287
        const int cidx = t & 127;
        const int f    = (t >> 7) & 31;
        const int bt16 = t >> 12;
        const int bp = cidx >> 3, x = cidx & 7;
        const int ec = x ^ (bp & 7);
        const float* src = emb + (((size_t)(bt16 * 16 + bp) * NF + f) * EMB + ec * 8);
        const f32x4 a = *(const f32x4*)src;
        const f32x4 b = *(const f32x4*)(src + 4);
        uint4 u;
        u.x = pack2(a[0], a[1]); u.y = pack2(a[2], a[3]);
        u.z = pack2(b[0], b[1]); u.w = pack2(b[2], b[3]);
        *(uint4*)(ebf + (size_t)t * 8) = u;
    }
}

__global__ __launch_bounds__(512, 4) void opnl_main(
    const short* __restrict__ ebf,   // [B/16][NF][128 chunks x 8 shorts] swizzled
    const short* __restrict__ kb,    // [NP][8][64][8] bf16 fragment order
    float* __restrict__ out)         // [B][NP] f32
{
    __shared__ short elds[16 * 2 * 1024];    // 32 segs x 2KB = 64KB

    const int type = blockIdx.x >> 6;        // 0..7
    const int bt   = blockIdx.x & 63;        // b-tile; bid%8 = bt%8 -> XCD share
    const int b0   = bt * BT;

    int bLo, bHi, npr;
    switch (type) {
        case 0: case 1: bLo = 0;  bHi = 0;  npr = 60; break;  // fields 0..15
        case 2: case 3: bLo = 16; bHi = 16; npr = 60; break;  // fields 16..31
        case 4:         bLo = 0;  bHi = 8;  npr = 64; break;
        case 5:         bLo = 8;  bHi = 16; npr = 64; break;
        case 6:         bLo = 0;  bHi = 16; npr = 64; break;
        default:        bLo = 8;  bHi = 8;  npr = 64; break;
    }

    const int lane = threadIdx.x & 63;
    const int wid  = threadIdx.x >> 6;       // 0..7
    const int lo4  = lane & 15;
    const int hi4  = lane >> 4;

    // ---- stage: wave w copies segs 4w..4w+3 (seg = lf*2+sub), 2x 1KB each
#pragma unroll
    for (int i = 0; i < 4; ++i) {
        const int s   = wid * 4 + i;
        const int lf  = s >> 1, sub = s & 1;
        const int gf  = lf + (lf < 8 ? bLo : bHi);
        const short* src = ebf + ((size_t)((bt * 2 + sub) * 32 + gf)) * 1024;
        __builtin_amdgcn_global_load_lds((const AS1 void*)(src + lane * 8),
                                         (AS3 void*)&elds[s * 1024], 16, 0, 0);
        __builtin_amdgcn_global_load_lds((const AS1 void*)(src + 512 + lane * 8),
                                         (AS3 void*)&elds[s * 1024 + 512], 16, 0, 0);
    }
    __syncthreads();

    // pair k (0..7) -> local fields (lr,lc) + global n ; wave-uniform
    auto pairK = [&](int k, int& lr, int& lc, int& nn) {
        int pr = wid + 8 * k;
        if (pr >= npr) pr -= npr;            // wrap: benign duplicate write
        if (type < 4) {
            int pig = (type & 1) * 60 + pr;  // triu16 index 0..119
            int r = 0;
            while (pig >= 15 - r) { pig -= 15 - r; ++r; }
            lr = r; lc = r + 1 + pig;
        } else {
            lr = pr >> 3; lc = 8 + (pr & 7);
        }
        const int R = lr + (lr < 8 ? bLo : bHi);
        const int C = lc + (lc < 8 ? bLo : bHi);
        nn = R * (63 - R) / 2 + (C - R - 1);
    };

    auto loadW = [&](bf16x8 (&wf)[4][2], int nn) {
        const bf16x8* wp = (const bf16x8*)(kb + (size_t)nn * 4096);
#pragma unroll
        for (int mh = 0; mh < 4; ++mh)
#pragma unroll
            for (int kc = 0; kc < 2; ++kc)
                wf[mh][kc] = wp[(mh * 2 + kc) * 64 + lane];   // 1KB coalesced
    };

    auto compute = [&](bf16x8 (&wf)[4][2], int lr, int lc, int nn) {
#pragma unroll
        for (int sub = 0; sub < 2; ++sub) {
            const int bb = sub * 16 + lo4;

            bf16x8 pf[2];
#pragma unroll
            for (int kc = 0; kc < 2; ++kc)
                pf[kc] = *(const bf16x8*)
                    &elds[(lr * 2 + sub) * 1024 +
                          (lo4 * 8 + (((kc * 4 + hi4) ^ (lo4 & 7)))) * 8];

            f32x4 acc[4] = {f32x4{0,0,0,0}, f32x4{0,0,0,0},
                            f32x4{0,0,0,0}, f32x4{0,0,0,0}};
#pragma unroll
            for (int mh = 0; mh < 4; ++mh)
#pragma unroll
                for (int kc = 0; kc < 2; ++kc)
                    acc[mh] = __builtin_amdgcn_mfma_f32_16x16x32_bf16(
                        wf[mh][kc], pf[kc], acc[mh], 0, 0, 0);

            float val = 0.f;
#pragma unroll
            for (int mh = 0; mh < 4; ++mh) {
                const bf16x4 q = *(const bf16x4*)
                    &elds[(lc * 2 + sub) * 1024 +
                          (lo4 * 8 + (((mh * 2 + (hi4 >> 1)) ^ (lo4 & 7)))) * 8 +
                          (hi4 & 1) * 4];
                val += acc[mh][0] * bf2f(q[0]) + acc[mh][1] * bf2f(q[1])
                     + acc[mh][2] * bf2f(q[2]) + acc[mh][3] * bf2f(q[3]);
            }
            val += __shfl_xor(val, 16, 64);
            val += __shfl_xor(val, 32, 64);
            if (lane < 16) out[(size_t)(b0 + bb) * NP + nn] = val;
        }
    };

    // ---- PROBE: run the 8-pair loop TWICE (idempotent duplicate stores).
    // rep-loop is not unrolled; iterations are identical by construction.
    for (int rep = 0; rep < 2; ++rep) {
        bf16x8 wA[4][2], wB[4][2];
        int lrA, lcA, nA, lrB, lcB, nB;
        pairK(0, lrA, lcA, nA);
        loadW(wA, nA);
#pragma unroll
        for (int k = 0; k < 8; ++k) {
            if ((k & 1) == 0) {
                if (k < 7) { pairK(k + 1, lrB, lcB, nB); loadW(wB, nB); }
                compute(wA, lrA, lcA, nA);
            } else {
                if (k < 7) { pairK(k + 1, lrA, lcA, nA); loadW(wA, nA); }
                compute(wB, lrB, lcB, nB);
            }
        }
    }
}

extern "C" void kernel_launch(void* const* d_in, const int* in_sizes, int n_in,
                              void* d_out, int out_size, void* d_ws, size_t ws_size,
                              hipStream_t stream) {
    const float* emb  = (const float*)d_in[0];   // 2048*32*64
    const float* kern = (const float*)d_in[1];   // 64*496*64
    float*       out  = (float*)d_out;           // 2048*496

    short* kb  = (short*)d_ws;                          // 496*4096 bf16 ~3.9MB
    short* ebf = (short*)((char*)d_ws + (4 << 20));     // 2048*32*64 bf16 = 8MB

    prep<<<NP + (B_TOT * NF * EMB / 8) / 256, 256, 0, stream>>>(kern, emb, kb, ebf);
    opnl_main<<<8 * 64, 512, 0, stream>>>(ebf, kb, out);   // 512 blocks
}